// Round 1
// baseline (310.769 us; speedup 1.0000x reference)
//
#include <hip/hip_runtime.h>
#include <hip/hip_bf16.h>

#define B_ROWS 8192
#define FEAT   1538

typedef float f32x4 __attribute__((ext_vector_type(4)));
typedef short s16x8 __attribute__((ext_vector_type(8)));

#if __has_builtin(__builtin_amdgcn_exp2f)
#define EXP2(x) __builtin_amdgcn_exp2f(x)
#else
#define EXP2(x) exp2f(x)
#endif

__device__ __forceinline__ unsigned short f2bf(float x) {
    __hip_bfloat16 h = __float2bfloat16(x);
    return *reinterpret_cast<unsigned short*>(&h);
}

// ---------------------------------------------------------------------------
// Kernel A: per 16-row block -> fm, X, and bf16 Qp/Kp/VpT
// block = 256 threads (4 waves). grid = 8192/16 = 512.
// ---------------------------------------------------------------------------
__global__ __launch_bounds__(256) void prep_kernel(
    const float* __restrict__ bd, const float* __restrict__ fm_w, const float* __restrict__ fm_b,
    const float* __restrict__ W_DA, const float* __restrict__ b_DA,
    const float* __restrict__ W_DM, const float* __restrict__ b_DM,
    const float* __restrict__ hDA, const float* __restrict__ hDM,
    const float* __restrict__ hCA, const float* __restrict__ hCM,
    const float* __restrict__ fvDA, const float* __restrict__ fvDM,
    const float* __restrict__ fvCA, const float* __restrict__ fvCM,
    const float* __restrict__ Qw, const float* __restrict__ Kw, const float* __restrict__ Vw,
    float* __restrict__ fm_out, unsigned short* __restrict__ Qp,
    unsigned short* __restrict__ Kp, unsigned short* __restrict__ VpT)
{
    __shared__ float s_bd[16][256];
    __shared__ float s_redDA[4][16][64];
    __shared__ float s_redDM[4][16][64];
    __shared__ float s_iDA [64][16];
    __shared__ float s_iDA2[64][16];
    __shared__ float s_iDM [64][16];
    __shared__ float s_iDM2[64][16];
    __shared__ float s_sc[16][4];     // sB_DA, sB_DM, cA, cM per row
    __shared__ float s_fm[4][16];
    __shared__ float s_X[64][16];
    __shared__ unsigned short s_vp[64][16];

    const int tid  = threadIdx.x;
    const int w    = tid >> 6;
    const int lane = tid & 63;
    const int r0   = blockIdx.x * 16;

    float aDA[16], aDM[16], fmp[16];
#pragma unroll
    for (int i = 0; i < 16; ++i) { aDA[i] = 0.f; aDM[i] = 0.f; fmp[i] = 0.f; }

    // ---- Phase 1: staged inter GEMMs (K split across 4 waves) + fm partials
    for (int c = 0; c < 6; ++c) {
#pragma unroll
        for (int i = 0; i < 16; ++i) {
            float v = bd[(size_t)(r0 + i) * FEAT + c * 256 + tid];
            s_bd[i][tid] = v;
            fmp[i] += v * fm_w[c * 256 + tid];
        }
        __syncthreads();
        const int kbase = w * 64;
        if (c < 3) {
            const float* Wp = W_DA + (size_t)(c * 256 + kbase) * 64 + lane;
#pragma unroll 2
            for (int k = 0; k < 64; k += 4) {
                float w0 = Wp[(k + 0) * 64], w1 = Wp[(k + 1) * 64];
                float w2 = Wp[(k + 2) * 64], w3 = Wp[(k + 3) * 64];
#pragma unroll
                for (int r = 0; r < 16; ++r) {
                    const f32x4 b4 = *(const f32x4*)&s_bd[r][kbase + k];
                    aDA[r] += b4.x * w0 + b4.y * w1 + b4.z * w2 + b4.w * w3;
                }
            }
        } else {
            const float* Wp = W_DM + (size_t)((c - 3) * 256 + kbase) * 64 + lane;
#pragma unroll 2
            for (int k = 0; k < 64; k += 4) {
                float w0 = Wp[(k + 0) * 64], w1 = Wp[(k + 1) * 64];
                float w2 = Wp[(k + 2) * 64], w3 = Wp[(k + 3) * 64];
#pragma unroll
                for (int r = 0; r < 16; ++r) {
                    const f32x4 b4 = *(const f32x4*)&s_bd[r][kbase + k];
                    aDM[r] += b4.x * w0 + b4.y * w1 + b4.z * w2 + b4.w * w3;
                }
            }
        }
        __syncthreads();
    }

    // ---- Phase 1.5: reductions
#pragma unroll
    for (int i = 0; i < 16; ++i) {
        float v = fmp[i];
        v += __shfl_xor(v, 1, 64);  v += __shfl_xor(v, 2, 64);
        v += __shfl_xor(v, 4, 64);  v += __shfl_xor(v, 8, 64);
        v += __shfl_xor(v, 16, 64); v += __shfl_xor(v, 32, 64);
        if (lane == 0) s_fm[w][i] = v;
    }
#pragma unroll
    for (int r = 0; r < 16; ++r) {
        s_redDA[w][r][lane] = aDA[r];
        s_redDM[w][r][lane] = aDM[r];
    }
    __syncthreads();

    {
        const float bda = b_DA[lane], bdm = b_DM[lane];
#pragma unroll
        for (int rr = 0; rr < 4; ++rr) {
            int r = w * 4 + rr;
            float ia = s_redDA[0][r][lane] + s_redDA[1][r][lane] +
                       s_redDA[2][r][lane] + s_redDA[3][r][lane] + bda;
            float im = s_redDM[0][r][lane] + s_redDM[1][r][lane] +
                       s_redDM[2][r][lane] + s_redDM[3][r][lane] + bdm;
            s_iDA[lane][r] = ia;  s_iDA2[lane][r] = ia * ia;
            s_iDM[lane][r] = im;  s_iDM2[lane][r] = im * im;
            float sa = ia, sm = im;
            sa += __shfl_xor(sa, 1, 64);  sa += __shfl_xor(sa, 2, 64);
            sa += __shfl_xor(sa, 4, 64);  sa += __shfl_xor(sa, 8, 64);
            sa += __shfl_xor(sa, 16, 64); sa += __shfl_xor(sa, 32, 64);
            sm += __shfl_xor(sm, 1, 64);  sm += __shfl_xor(sm, 2, 64);
            sm += __shfl_xor(sm, 4, 64);  sm += __shfl_xor(sm, 8, 64);
            sm += __shfl_xor(sm, 16, 64); sm += __shfl_xor(sm, 32, 64);
            if (lane == 0) { s_sc[r][0] = sa; s_sc[r][1] = sm; }
        }
    }
    if (w == 0 && lane < 16) {
        int r = lane;
        float cA = bd[(size_t)(r0 + r) * FEAT + 1536];
        float cM = bd[(size_t)(r0 + r) * FEAT + 1537];
        s_sc[r][2] = cA; s_sc[r][3] = cM;
        float f = s_fm[0][r] + s_fm[1][r] + s_fm[2][r] + s_fm[3][r]
                + cA * fm_w[1536] + cM * fm_w[1537] + fm_b[0];
        fm_out[r0 + r] = f;
    }
    __syncthreads();

    // ---- Phase 2: bi-pooling sums + X (wave w owns rows 4w..4w+3, lane = h)
    float sADA[4] = {0,0,0,0}, sqDA[4] = {0,0,0,0};
    float sADM[4] = {0,0,0,0}, sqDM[4] = {0,0,0,0};
    const int rbase = w * 4;
    for (int e2 = 0; e2 < 64; ++e2) {
        float ha = hDA[e2 * 64 + lane], hm = hDM[e2 * 64 + lane];
        float ha2 = ha * ha, hm2 = hm * hm;
        f32x4 ia  = *(const f32x4*)&s_iDA [e2][rbase];
        f32x4 ia2 = *(const f32x4*)&s_iDA2[e2][rbase];
        f32x4 im  = *(const f32x4*)&s_iDM [e2][rbase];
        f32x4 im2 = *(const f32x4*)&s_iDM2[e2][rbase];
#pragma unroll
        for (int rr = 0; rr < 4; ++rr) {
            sADA[rr] += ia[rr] * ha;  sqDA[rr] += ia2[rr] * ha2;
            sADM[rr] += im[rr] * hm;  sqDM[rr] += im2[rr] * hm2;
        }
    }
    {
        const float fva = fvDA[lane], fvm = fvDM[lane];
        const float fvca = fvCA[lane], fvcm = fvCM[lane];
        const float hca = hCA[lane],  hcm = hCM[lane];
#pragma unroll
        for (int rr = 0; rr < 4; ++rr) {
            int r = rbase + rr;
            float sBDA = s_sc[r][0], sBDM = s_sc[r][1];
            float cA = s_sc[r][2],   cM = s_sc[r][3];
            float biA = 0.5f * (sADA[rr] * sADA[rr] - sqDA[rr]);
            float biM = 0.5f * (sADM[rr] * sADM[rr] - sqDM[rr]);
            float X = biA + biM
                + sADA[rr] * (fvm * sBDM + fvca * cA + fvcm * cM)
                + sADM[rr] * (fva * sBDA + fvca * cA + fvcm * cM)
                + cA * hca * (fva * sBDA + fvm * sBDM + fvcm * cM)
                + cM * hcm * (fva * sBDA + fvm * sBDM + fvca * cA);
            s_X[lane][r] = X;
        }
    }
    __syncthreads();

    // ---- Phase 3: QKV projection (lane = output col j)
    float aQ[4] = {0,0,0,0}, aK[4] = {0,0,0,0}, aV[4] = {0,0,0,0};
    for (int h2 = 0; h2 < 64; ++h2) {
        float q = Qw[h2 * 64 + lane], k = Kw[h2 * 64 + lane], v = Vw[h2 * 64 + lane];
        f32x4 x = *(const f32x4*)&s_X[h2][rbase];
#pragma unroll
        for (int rr = 0; rr < 4; ++rr) {
            aQ[rr] += x[rr] * q; aK[rr] += x[rr] * k; aV[rr] += x[rr] * v;
        }
    }
    const float LOG2E = 1.4426950408889634f;
#pragma unroll
    for (int rr = 0; rr < 4; ++rr) {
        int r = rbase + rr;
        Qp[(size_t)(r0 + r) * 64 + lane] = f2bf(aQ[rr] * LOG2E);
        Kp[(size_t)(r0 + r) * 64 + lane] = f2bf(aK[rr]);
        s_vp[lane][r] = f2bf(aV[rr]);
    }
    __syncthreads();
    if (tid < 64) {
        const uint4* src = (const uint4*)&s_vp[tid][0];   // 16 bf16 = 32 B
        uint4* dst = (uint4*)(VpT + (size_t)tid * B_ROWS + r0);
        dst[0] = src[0]; dst[1] = src[1];
    }
}

// ---------------------------------------------------------------------------
// Kernel B: flash attention (no-max online softmax; logits are O(0.05)) +
// fused relu((vw@W1)/sqrt(1+eps)), h@W2, sigmoid epilogue.
// block = 256 threads (4 waves). Each wave: 16 q-rows x 2048-key split.
// grid = 8192/16 = 512.
// ---------------------------------------------------------------------------
__global__ __launch_bounds__(256) void attn_kernel(
    const unsigned short* __restrict__ Qp, const unsigned short* __restrict__ Kp,
    const unsigned short* __restrict__ VpT, const float* __restrict__ fm,
    const float* __restrict__ W1, const float* __restrict__ b1,
    const float* __restrict__ W2, const float* __restrict__ b2,
    float* __restrict__ out)
{
    __shared__ unsigned short s_P[4][16][72];   // per-wave P tile, padded rows (144B, 16B-aligned)
    __shared__ float s_O[4][16][64];
    __shared__ float s_l[4][16];
    __shared__ float s_ep[16][17];

    const int tid = threadIdx.x;
    const int w = tid >> 6, lane = tid & 63;
    const int l15 = lane & 15, lhi = lane >> 4;
    const int qr0 = blockIdx.x * 16;

    s16x8 QA[2];
#pragma unroll
    for (int kk = 0; kk < 2; ++kk)
        QA[kk] = *(const s16x8*)(Qp + (size_t)(qr0 + l15) * 64 + kk * 32 + lhi * 8);

    f32x4 accO[4];
#pragma unroll
    for (int ht = 0; ht < 4; ++ht) accO[ht] = (f32x4){0.f, 0.f, 0.f, 0.f};
    float lp[4] = {0.f, 0.f, 0.f, 0.f};
    const f32x4 zero4 = (f32x4){0.f, 0.f, 0.f, 0.f};

    const int key0 = w * 2048;
    for (int it = 0; it < 32; ++it) {
        const int kc0 = key0 + it * 64;
        s16x8 KB[4][2];
#pragma unroll
        for (int nt = 0; nt < 4; ++nt)
#pragma unroll
            for (int kk = 0; kk < 2; ++kk)
                KB[nt][kk] = *(const s16x8*)(Kp + (size_t)(kc0 + nt * 16 + l15) * 64 + kk * 32 + lhi * 8);

        f32x4 accS[4];
#pragma unroll
        for (int nt = 0; nt < 4; ++nt) {
            accS[nt] = __builtin_amdgcn_mfma_f32_16x16x32_bf16(QA[0], KB[nt][0], zero4, 0, 0, 0);
            accS[nt] = __builtin_amdgcn_mfma_f32_16x16x32_bf16(QA[1], KB[nt][1], accS[nt], 0, 0, 0);
        }
        // P = exp2(S); Qp carries log2(e). C-layout: row=(lane>>4)*4+reg, col=lane&15.
#pragma unroll
        for (int nt = 0; nt < 4; ++nt)
#pragma unroll
            for (int reg = 0; reg < 4; ++reg) {
                float p = EXP2(accS[nt][reg]);
                lp[reg] += p;
                s_P[w][lhi * 4 + reg][nt * 16 + l15] = f2bf(p);
            }
        asm volatile("s_waitcnt lgkmcnt(0)" ::: "memory");
        __builtin_amdgcn_sched_barrier(0);

        s16x8 PA[2];
#pragma unroll
        for (int kk = 0; kk < 2; ++kk)
            PA[kk] = *(const s16x8*)&s_P[w][l15][kk * 32 + lhi * 8];
        s16x8 VB[4][2];
#pragma unroll
        for (int ht = 0; ht < 4; ++ht)
#pragma unroll
            for (int kk = 0; kk < 2; ++kk)
                VB[ht][kk] = *(const s16x8*)(VpT + (size_t)(ht * 16 + l15) * B_ROWS + kc0 + kk * 32 + lhi * 8);
#pragma unroll
        for (int ht = 0; ht < 4; ++ht) {
            accO[ht] = __builtin_amdgcn_mfma_f32_16x16x32_bf16(PA[0], VB[ht][0], accO[ht], 0, 0, 0);
            accO[ht] = __builtin_amdgcn_mfma_f32_16x16x32_bf16(PA[1], VB[ht][1], accO[ht], 0, 0, 0);
        }
        __builtin_amdgcn_sched_barrier(0);
    }

    // deferred row-sum reduce (rows live in 16-lane groups)
#pragma unroll
    for (int reg = 0; reg < 4; ++reg) {
        float v = lp[reg];
        v += __shfl_xor(v, 1, 64); v += __shfl_xor(v, 2, 64);
        v += __shfl_xor(v, 4, 64); v += __shfl_xor(v, 8, 64);
        lp[reg] = v;
    }
    if (l15 == 0) {
#pragma unroll
        for (int reg = 0; reg < 4; ++reg) s_l[w][lhi * 4 + reg] = lp[reg];
    }
#pragma unroll
    for (int ht = 0; ht < 4; ++ht)
#pragma unroll
        for (int reg = 0; reg < 4; ++reg)
            s_O[w][lhi * 4 + reg][ht * 16 + l15] = accO[ht][reg];
    __syncthreads();

    // epilogue: merge 4 key-splits, h = relu((vw@W1)/sqrt(1+eps)), h@W2, sigmoid
    {
        const int r = tid & 15, jg = tid >> 4;
        const float Lr = s_l[0][r] + s_l[1][r] + s_l[2][r] + s_l[3][r];
        const float invL = 1.0f / Lr;
        const float invs = 0.9999950000374997f;   // 1/sqrt(1+1e-5)
        float d[4] = {0.f, 0.f, 0.f, 0.f};
        for (int c = 0; c < 64; ++c) {
            float o = s_O[0][r][c] + s_O[1][r][c] + s_O[2][r][c] + s_O[3][r][c];
#pragma unroll
            for (int jj = 0; jj < 4; ++jj) d[jj] += o * W1[c * 64 + jg * 4 + jj];
        }
        float acc = 0.f;
#pragma unroll
        for (int jj = 0; jj < 4; ++jj) {
            int j = jg * 4 + jj;
            float hv = invs * (d[jj] * invL + b1[j]);
            hv = fmaxf(hv, 0.f);
            acc += hv * W2[j];
        }
        s_ep[r][jg] = acc;
    }
    __syncthreads();
    if (tid < 16) {
        int r = tid;
        float s = 0.f;
#pragma unroll
        for (int jg = 0; jg < 16; ++jg) s += s_ep[r][jg];
        float z = fm[qr0 + r] + s + b2[0];
        out[qr0 + r] = 1.0f / (1.0f + __expf(-z));
    }
}

extern "C" void kernel_launch(void* const* d_in, const int* in_sizes, int n_in,
                              void* d_out, int out_size, void* d_ws, size_t ws_size,
                              hipStream_t stream) {
    const float* bd   = (const float*)d_in[0];
    const float* fm_w = (const float*)d_in[1];
    const float* fm_b = (const float*)d_in[2];
    const float* W_DA = (const float*)d_in[3];
    const float* b_DA = (const float*)d_in[4];
    const float* W_DM = (const float*)d_in[5];
    const float* b_DM = (const float*)d_in[6];
    const float* hDA  = (const float*)d_in[7];
    const float* hDM  = (const float*)d_in[8];
    const float* hCA  = (const float*)d_in[9];
    const float* hCM  = (const float*)d_in[10];
    const float* fvDA = (const float*)d_in[11];
    const float* fvDM = (const float*)d_in[12];
    const float* fvCA = (const float*)d_in[13];
    const float* fvCM = (const float*)d_in[14];
    const float* Qw   = (const float*)d_in[15];
    const float* Kw   = (const float*)d_in[16];
    const float* Vw   = (const float*)d_in[17];
    const float* W1   = (const float*)d_in[18];
    const float* b1   = (const float*)d_in[19];
    const float* W2   = (const float*)d_in[20];
    const float* b2   = (const float*)d_in[21];

    char* ws = (char*)d_ws;
    float*          fmv = (float*)ws;                                  // 32 KB
    unsigned short* Qp  = (unsigned short*)(ws + 32768);               // 1 MB
    unsigned short* Kp  = (unsigned short*)(ws + 32768 + 1048576);     // 1 MB
    unsigned short* VpT = (unsigned short*)(ws + 32768 + 2097152);     // 1 MB

    hipLaunchKernelGGL(prep_kernel, dim3(512), dim3(256), 0, stream,
        bd, fm_w, fm_b, W_DA, b_DA, W_DM, b_DM, hDA, hDM, hCA, hCM,
        fvDA, fvDM, fvCA, fvCM, Qw, Kw, Vw, fmv, Qp, Kp, VpT);

    hipLaunchKernelGGL(attn_kernel, dim3(512), dim3(256), 0, stream,
        Qp, Kp, VpT, fmv, W1, b1, W2, b2, (float*)d_out);
}

// Round 2
// 309.581 us; speedup vs baseline: 1.0038x; 1.0038x over previous
//
#include <hip/hip_runtime.h>
#include <hip/hip_bf16.h>

#define B_ROWS 8192
#define FEAT   1538

typedef float f32x4 __attribute__((ext_vector_type(4)));
typedef short s16x8 __attribute__((ext_vector_type(8)));

#if __has_builtin(__builtin_amdgcn_exp2f)
#define EXP2(x) __builtin_amdgcn_exp2f(x)
#else
#define EXP2(x) exp2f(x)
#endif

__device__ __forceinline__ unsigned short f2bf(float x) {
    __hip_bfloat16 h = __float2bfloat16(x);
    return *reinterpret_cast<unsigned short*>(&h);
}

// ---------------------------------------------------------------------------
// Kernel A: per 16-row block -> fm, X, and bf16 Qp/Kp/VpT
// block = 256 threads (4 waves). grid = 8192/16 = 512.   (unchanged)
// ---------------------------------------------------------------------------
__global__ __launch_bounds__(256) void prep_kernel(
    const float* __restrict__ bd, const float* __restrict__ fm_w, const float* __restrict__ fm_b,
    const float* __restrict__ W_DA, const float* __restrict__ b_DA,
    const float* __restrict__ W_DM, const float* __restrict__ b_DM,
    const float* __restrict__ hDA, const float* __restrict__ hDM,
    const float* __restrict__ hCA, const float* __restrict__ hCM,
    const float* __restrict__ fvDA, const float* __restrict__ fvDM,
    const float* __restrict__ fvCA, const float* __restrict__ fvCM,
    const float* __restrict__ Qw, const float* __restrict__ Kw, const float* __restrict__ Vw,
    float* __restrict__ fm_out, unsigned short* __restrict__ Qp,
    unsigned short* __restrict__ Kp, unsigned short* __restrict__ VpT)
{
    __shared__ float s_bd[16][256];
    __shared__ float s_redDA[4][16][64];
    __shared__ float s_redDM[4][16][64];
    __shared__ float s_iDA [64][16];
    __shared__ float s_iDA2[64][16];
    __shared__ float s_iDM [64][16];
    __shared__ float s_iDM2[64][16];
    __shared__ float s_sc[16][4];     // sB_DA, sB_DM, cA, cM per row
    __shared__ float s_fm[4][16];
    __shared__ float s_X[64][16];
    __shared__ unsigned short s_vp[64][16];

    const int tid  = threadIdx.x;
    const int w    = tid >> 6;
    const int lane = tid & 63;
    const int r0   = blockIdx.x * 16;

    float aDA[16], aDM[16], fmp[16];
#pragma unroll
    for (int i = 0; i < 16; ++i) { aDA[i] = 0.f; aDM[i] = 0.f; fmp[i] = 0.f; }

    // ---- Phase 1: staged inter GEMMs (K split across 4 waves) + fm partials
    for (int c = 0; c < 6; ++c) {
#pragma unroll
        for (int i = 0; i < 16; ++i) {
            float v = bd[(size_t)(r0 + i) * FEAT + c * 256 + tid];
            s_bd[i][tid] = v;
            fmp[i] += v * fm_w[c * 256 + tid];
        }
        __syncthreads();
        const int kbase = w * 64;
        if (c < 3) {
            const float* Wp = W_DA + (size_t)(c * 256 + kbase) * 64 + lane;
#pragma unroll 2
            for (int k = 0; k < 64; k += 4) {
                float w0 = Wp[(k + 0) * 64], w1 = Wp[(k + 1) * 64];
                float w2 = Wp[(k + 2) * 64], w3 = Wp[(k + 3) * 64];
#pragma unroll
                for (int r = 0; r < 16; ++r) {
                    const f32x4 b4 = *(const f32x4*)&s_bd[r][kbase + k];
                    aDA[r] += b4.x * w0 + b4.y * w1 + b4.z * w2 + b4.w * w3;
                }
            }
        } else {
            const float* Wp = W_DM + (size_t)((c - 3) * 256 + kbase) * 64 + lane;
#pragma unroll 2
            for (int k = 0; k < 64; k += 4) {
                float w0 = Wp[(k + 0) * 64], w1 = Wp[(k + 1) * 64];
                float w2 = Wp[(k + 2) * 64], w3 = Wp[(k + 3) * 64];
#pragma unroll
                for (int r = 0; r < 16; ++r) {
                    const f32x4 b4 = *(const f32x4*)&s_bd[r][kbase + k];
                    aDM[r] += b4.x * w0 + b4.y * w1 + b4.z * w2 + b4.w * w3;
                }
            }
        }
        __syncthreads();
    }

    // ---- Phase 1.5: reductions
#pragma unroll
    for (int i = 0; i < 16; ++i) {
        float v = fmp[i];
        v += __shfl_xor(v, 1, 64);  v += __shfl_xor(v, 2, 64);
        v += __shfl_xor(v, 4, 64);  v += __shfl_xor(v, 8, 64);
        v += __shfl_xor(v, 16, 64); v += __shfl_xor(v, 32, 64);
        if (lane == 0) s_fm[w][i] = v;
    }
#pragma unroll
    for (int r = 0; r < 16; ++r) {
        s_redDA[w][r][lane] = aDA[r];
        s_redDM[w][r][lane] = aDM[r];
    }
    __syncthreads();

    {
        const float bda = b_DA[lane], bdm = b_DM[lane];
#pragma unroll
        for (int rr = 0; rr < 4; ++rr) {
            int r = w * 4 + rr;
            float ia = s_redDA[0][r][lane] + s_redDA[1][r][lane] +
                       s_redDA[2][r][lane] + s_redDA[3][r][lane] + bda;
            float im = s_redDM[0][r][lane] + s_redDM[1][r][lane] +
                       s_redDM[2][r][lane] + s_redDM[3][r][lane] + bdm;
            s_iDA[lane][r] = ia;  s_iDA2[lane][r] = ia * ia;
            s_iDM[lane][r] = im;  s_iDM2[lane][r] = im * im;
            float sa = ia, sm = im;
            sa += __shfl_xor(sa, 1, 64);  sa += __shfl_xor(sa, 2, 64);
            sa += __shfl_xor(sa, 4, 64);  sa += __shfl_xor(sa, 8, 64);
            sa += __shfl_xor(sa, 16, 64); sa += __shfl_xor(sa, 32, 64);
            sm += __shfl_xor(sm, 1, 64);  sm += __shfl_xor(sm, 2, 64);
            sm += __shfl_xor(sm, 4, 64);  sm += __shfl_xor(sm, 8, 64);
            sm += __shfl_xor(sm, 16, 64); sm += __shfl_xor(sm, 32, 64);
            if (lane == 0) { s_sc[r][0] = sa; s_sc[r][1] = sm; }
        }
    }
    if (w == 0 && lane < 16) {
        int r = lane;
        float cA = bd[(size_t)(r0 + r) * FEAT + 1536];
        float cM = bd[(size_t)(r0 + r) * FEAT + 1537];
        s_sc[r][2] = cA; s_sc[r][3] = cM;
        float f = s_fm[0][r] + s_fm[1][r] + s_fm[2][r] + s_fm[3][r]
                + cA * fm_w[1536] + cM * fm_w[1537] + fm_b[0];
        fm_out[r0 + r] = f;
    }
    __syncthreads();

    // ---- Phase 2: bi-pooling sums + X (wave w owns rows 4w..4w+3, lane = h)
    float sADA[4] = {0,0,0,0}, sqDA[4] = {0,0,0,0};
    float sADM[4] = {0,0,0,0}, sqDM[4] = {0,0,0,0};
    const int rbase = w * 4;
    for (int e2 = 0; e2 < 64; ++e2) {
        float ha = hDA[e2 * 64 + lane], hm = hDM[e2 * 64 + lane];
        float ha2 = ha * ha, hm2 = hm * hm;
        f32x4 ia  = *(const f32x4*)&s_iDA [e2][rbase];
        f32x4 ia2 = *(const f32x4*)&s_iDA2[e2][rbase];
        f32x4 im  = *(const f32x4*)&s_iDM [e2][rbase];
        f32x4 im2 = *(const f32x4*)&s_iDM2[e2][rbase];
#pragma unroll
        for (int rr = 0; rr < 4; ++rr) {
            sADA[rr] += ia[rr] * ha;  sqDA[rr] += ia2[rr] * ha2;
            sADM[rr] += im[rr] * hm;  sqDM[rr] += im2[rr] * hm2;
        }
    }
    {
        const float fva = fvDA[lane], fvm = fvDM[lane];
        const float fvca = fvCA[lane], fvcm = fvCM[lane];
        const float hca = hCA[lane],  hcm = hCM[lane];
#pragma unroll
        for (int rr = 0; rr < 4; ++rr) {
            int r = rbase + rr;
            float sBDA = s_sc[r][0], sBDM = s_sc[r][1];
            float cA = s_sc[r][2],   cM = s_sc[r][3];
            float biA = 0.5f * (sADA[rr] * sADA[rr] - sqDA[rr]);
            float biM = 0.5f * (sADM[rr] * sADM[rr] - sqDM[rr]);
            float X = biA + biM
                + sADA[rr] * (fvm * sBDM + fvca * cA + fvcm * cM)
                + sADM[rr] * (fva * sBDA + fvca * cA + fvcm * cM)
                + cA * hca * (fva * sBDA + fvm * sBDM + fvcm * cM)
                + cM * hcm * (fva * sBDA + fvm * sBDM + fvca * cA);
            s_X[lane][r] = X;
        }
    }
    __syncthreads();

    // ---- Phase 3: QKV projection (lane = output col j)
    float aQ[4] = {0,0,0,0}, aK[4] = {0,0,0,0}, aV[4] = {0,0,0,0};
    for (int h2 = 0; h2 < 64; ++h2) {
        float q = Qw[h2 * 64 + lane], k = Kw[h2 * 64 + lane], v = Vw[h2 * 64 + lane];
        f32x4 x = *(const f32x4*)&s_X[h2][rbase];
#pragma unroll
        for (int rr = 0; rr < 4; ++rr) {
            aQ[rr] += x[rr] * q; aK[rr] += x[rr] * k; aV[rr] += x[rr] * v;
        }
    }
    const float LOG2E = 1.4426950408889634f;
#pragma unroll
    for (int rr = 0; rr < 4; ++rr) {
        int r = rbase + rr;
        Qp[(size_t)(r0 + r) * 64 + lane] = f2bf(aQ[rr] * LOG2E);
        Kp[(size_t)(r0 + r) * 64 + lane] = f2bf(aK[rr]);
        s_vp[lane][r] = f2bf(aV[rr]);
    }
    __syncthreads();
    if (tid < 64) {
        const uint4* src = (const uint4*)&s_vp[tid][0];   // 16 bf16 = 32 B
        uint4* dst = (uint4*)(VpT + (size_t)tid * B_ROWS + r0);
        dst[0] = src[0]; dst[1] = src[1];
    }
}

// ---------------------------------------------------------------------------
// Kernel B: flash attention, register-double-buffered K/V prefetch.
// block = 256 threads (4 waves). Each wave: 16 q-rows x 2048-key split.
// grid = 512. No sched_barriers -> compiler emits counted vmcnt/lgkmcnt.
// ---------------------------------------------------------------------------
__global__ __launch_bounds__(256, 2) void attn_kernel(
    const unsigned short* __restrict__ Qp, const unsigned short* __restrict__ Kp,
    const unsigned short* __restrict__ VpT, const float* __restrict__ fm,
    const float* __restrict__ W1, const float* __restrict__ b1,
    const float* __restrict__ W2, const float* __restrict__ b2,
    float* __restrict__ out)
{
    __shared__ unsigned short s_P[4][16][72];   // per-wave P tile, padded rows
    __shared__ float s_O[4][16][64];
    __shared__ float s_l[4][16];
    __shared__ float s_ep[16][17];

    const int tid = threadIdx.x;
    const int w = tid >> 6, lane = tid & 63;
    const int l15 = lane & 15, lhi = lane >> 4;
    const int qr0 = blockIdx.x * 16;

    s16x8 QA[2];
#pragma unroll
    for (int kk = 0; kk < 2; ++kk)
        QA[kk] = *(const s16x8*)(Qp + (size_t)(qr0 + l15) * 64 + kk * 32 + lhi * 8);

    f32x4 accO[4];
#pragma unroll
    for (int ht = 0; ht < 4; ++ht) accO[ht] = (f32x4){0.f, 0.f, 0.f, 0.f};
    float lp[4] = {0.f, 0.f, 0.f, 0.f};
    const f32x4 zero4 = (f32x4){0.f, 0.f, 0.f, 0.f};

    const int key0 = w * 2048;

    // issue 16 global loads for key-tile `it` into the given register set
    auto LOADKV = [&](s16x8 (&Kd)[4][2], s16x8 (&Vd)[4][2], int it) {
        const int kc = key0 + it * 64;
#pragma unroll
        for (int nt = 0; nt < 4; ++nt)
#pragma unroll
            for (int kk = 0; kk < 2; ++kk) {
                Kd[nt][kk] = *(const s16x8*)(Kp + (size_t)(kc + nt * 16 + l15) * 64 + kk * 32 + lhi * 8);
                Vd[nt][kk] = *(const s16x8*)(VpT + (size_t)(nt * 16 + l15) * B_ROWS + kc + kk * 32 + lhi * 8);
            }
    };

    // QK^T -> exp2 -> P (LDS layout change) -> PV, for one 64-key tile
    auto COMPUTE = [&](s16x8 (&Kb)[4][2], s16x8 (&Vb)[4][2]) {
        f32x4 accS[4];
#pragma unroll
        for (int nt = 0; nt < 4; ++nt) {
            accS[nt] = __builtin_amdgcn_mfma_f32_16x16x32_bf16(QA[0], Kb[nt][0], zero4, 0, 0, 0);
            accS[nt] = __builtin_amdgcn_mfma_f32_16x16x32_bf16(QA[1], Kb[nt][1], accS[nt], 0, 0, 0);
        }
        // P = exp2(S); Qp carries log2(e). C-layout: row=(lane>>4)*4+reg, col=lane&15.
#pragma unroll
        for (int nt = 0; nt < 4; ++nt)
#pragma unroll
            for (int reg = 0; reg < 4; ++reg) {
                float p = EXP2(accS[nt][reg]);
                lp[reg] += p;
                s_P[w][lhi * 4 + reg][nt * 16 + l15] = f2bf(p);
            }
        s16x8 PA[2];
#pragma unroll
        for (int kk = 0; kk < 2; ++kk)
            PA[kk] = *(const s16x8*)&s_P[w][l15][kk * 32 + lhi * 8];
#pragma unroll
        for (int ht = 0; ht < 4; ++ht) {
            accO[ht] = __builtin_amdgcn_mfma_f32_16x16x32_bf16(PA[0], Vb[ht][0], accO[ht], 0, 0, 0);
            accO[ht] = __builtin_amdgcn_mfma_f32_16x16x32_bf16(PA[1], Vb[ht][1], accO[ht], 0, 0, 0);
        }
    };

    s16x8 KAr[4][2], VAr[4][2], KBr[4][2], VBr[4][2];
    LOADKV(KAr, VAr, 0);
    for (int it = 0; it < 32; it += 2) {
        LOADKV(KBr, VBr, it + 1);        // prefetch next tile while computing current
        COMPUTE(KAr, VAr);
        if (it < 30) LOADKV(KAr, VAr, it + 2);
        COMPUTE(KBr, VBr);
    }

    // deferred row-sum reduce (rows live in 16-lane groups)
#pragma unroll
    for (int reg = 0; reg < 4; ++reg) {
        float v = lp[reg];
        v += __shfl_xor(v, 1, 64); v += __shfl_xor(v, 2, 64);
        v += __shfl_xor(v, 4, 64); v += __shfl_xor(v, 8, 64);
        lp[reg] = v;
    }
    if (l15 == 0) {
#pragma unroll
        for (int reg = 0; reg < 4; ++reg) s_l[w][lhi * 4 + reg] = lp[reg];
    }
#pragma unroll
    for (int ht = 0; ht < 4; ++ht)
#pragma unroll
        for (int reg = 0; reg < 4; ++reg)
            s_O[w][lhi * 4 + reg][ht * 16 + l15] = accO[ht][reg];
    __syncthreads();

    // epilogue: merge 4 key-splits, h = relu((vw@W1)/sqrt(1+eps)), h@W2, sigmoid
    {
        const int r = tid & 15, jg = tid >> 4;
        const float Lr = s_l[0][r] + s_l[1][r] + s_l[2][r] + s_l[3][r];
        const float invL = 1.0f / Lr;
        const float invs = 0.9999950000374997f;   // 1/sqrt(1+1e-5)
        float d[4] = {0.f, 0.f, 0.f, 0.f};
        for (int c = 0; c < 64; ++c) {
            float o = s_O[0][r][c] + s_O[1][r][c] + s_O[2][r][c] + s_O[3][r][c];
#pragma unroll
            for (int jj = 0; jj < 4; ++jj) d[jj] += o * W1[c * 64 + jg * 4 + jj];
        }
        float acc = 0.f;
#pragma unroll
        for (int jj = 0; jj < 4; ++jj) {
            int j = jg * 4 + jj;
            float hv = invs * (d[jj] * invL + b1[j]);
            hv = fmaxf(hv, 0.f);
            acc += hv * W2[j];
        }
        s_ep[r][jg] = acc;
    }
    __syncthreads();
    if (tid < 16) {
        int r = tid;
        float s = 0.f;
#pragma unroll
        for (int jg = 0; jg < 16; ++jg) s += s_ep[r][jg];
        float z = fm[qr0 + r] + s + b2[0];
        out[qr0 + r] = 1.0f / (1.0f + __expf(-z));
    }
}

extern "C" void kernel_launch(void* const* d_in, const int* in_sizes, int n_in,
                              void* d_out, int out_size, void* d_ws, size_t ws_size,
                              hipStream_t stream) {
    const float* bd   = (const float*)d_in[0];
    const float* fm_w = (const float*)d_in[1];
    const float* fm_b = (const float*)d_in[2];
    const float* W_DA = (const float*)d_in[3];
    const float* b_DA = (const float*)d_in[4];
    const float* W_DM = (const float*)d_in[5];
    const float* b_DM = (const float*)d_in[6];
    const float* hDA  = (const float*)d_in[7];
    const float* hDM  = (const float*)d_in[8];
    const float* hCA  = (const float*)d_in[9];
    const float* hCM  = (const float*)d_in[10];
    const float* fvDA = (const float*)d_in[11];
    const float* fvDM = (const float*)d_in[12];
    const float* fvCA = (const float*)d_in[13];
    const float* fvCM = (const float*)d_in[14];
    const float* Qw   = (const float*)d_in[15];
    const float* Kw   = (const float*)d_in[16];
    const float* Vw   = (const float*)d_in[17];
    const float* W1   = (const float*)d_in[18];
    const float* b1   = (const float*)d_in[19];
    const float* W2   = (const float*)d_in[20];
    const float* b2   = (const float*)d_in[21];

    char* ws = (char*)d_ws;
    float*          fmv = (float*)ws;                                  // 32 KB
    unsigned short* Qp  = (unsigned short*)(ws + 32768);               // 1 MB
    unsigned short* Kp  = (unsigned short*)(ws + 32768 + 1048576);     // 1 MB
    unsigned short* VpT = (unsigned short*)(ws + 32768 + 2097152);     // 1 MB

    hipLaunchKernelGGL(prep_kernel, dim3(512), dim3(256), 0, stream,
        bd, fm_w, fm_b, W_DA, b_DA, W_DM, b_DM, hDA, hDM, hCA, hCM,
        fvDA, fvDM, fvCA, fvCM, Qw, Kw, Vw, fmv, Qp, Kp, VpT);

    hipLaunchKernelGGL(attn_kernel, dim3(512), dim3(256), 0, stream,
        Qp, Kp, VpT, fmv, W1, b1, W2, b2, (float*)d_out);
}